// Round 1
// 437.241 us; speedup vs baseline: 1.0007x; 1.0007x over previous
//
#include <hip/hip_runtime.h>
#include <hip/hip_bf16.h>
#include <stdint.h>

// GAT layer, MI355X. N=8192, F_in=256, F_out=128. All-f32 I/O.
// R12: k_attn re-staged — HS via global_load_lds (16B) into double-buffered
// unpadded [128][64] tile with XOR slot-swizzle (source pre-swizzled, read
// swizzled: rule 21), ONE __syncthreads per chunk (T3 2-phase), s2 staged in
// regs instead of LDS, setprio around MFMA cluster (T5). k_max fused into
// k_xw (per-block maxima) + k_attn prologue reduce. k_xw/k_comb otherwise
// unchanged from green R10/R11.

#define N_NODES 8192
#define F_INF   256
#define F_OUT   128
#define LRELU   0.01f

typedef __bf16 bf16x8 __attribute__((ext_vector_type(8)));
typedef float  f32x4  __attribute__((ext_vector_type(4)));
using bf16 = __hip_bfloat16;

__device__ __forceinline__ float b2f(bf16 v) { return __bfloat162float(v); }
__device__ __forceinline__ bf16  f2b(float v) { return __float2bfloat16(v); }

__device__ __forceinline__ void gll16(const void* g, void* l) {
    __builtin_amdgcn_global_load_lds(
        (const __attribute__((address_space(1))) uint32_t*)g,
        (__attribute__((address_space(3))) uint32_t*)l, 16, 0, 0);
}

// ---------------- kernel 1: h=x@W (split bf16), fused s1/s2, hT bf16, block max ----------------
// block: 32 rows, 256 threads (4 waves). wave -> rt=wave&1 (row-tile), cH=wave>>1 (f-half).
__global__ __launch_bounds__(256) void k_xw(const float* __restrict__ x,
                                            const float* __restrict__ W,
                                            const float* __restrict__ a,
                                            bf16* __restrict__ hT,
                                            float* __restrict__ s1,
                                            float* __restrict__ s2,
                                            float* __restrict__ mgp) {
    __shared__ __align__(16) bf16 WTh[F_OUT][F_INF + 8];
    __shared__ __align__(16) bf16 WTl[F_OUT][F_INF + 8];
    __shared__ __align__(16) bf16 XSh[32][72];
    __shared__ __align__(16) bf16 XSl[32][72];
    __shared__ float a1s[F_OUT], a2s[F_OUT], s1L[32], s2L[32];
    const int tid  = threadIdx.x;
    const int lane = tid & 63, wave = tid >> 6;
    const int i0   = blockIdx.x * 32;
    if (tid < F_OUT) { a1s[tid] = a[tid]; a2s[tid] = a[tid + F_OUT]; }
    if (tid < 32)    { s1L[tid] = 0.f; s2L[tid] = 0.f; }
    for (int idx = tid; idx < (F_INF * F_OUT) / 8; idx += 256) {
        int k  = idx >> 4;
        int n0 = (idx & 15) * 8;
        const float* src = W + (size_t)k * F_OUT + n0;
        float4 va = *(const float4*)(src);
        float4 vb = *(const float4*)(src + 4);
        float v[8] = {va.x, va.y, va.z, va.w, vb.x, vb.y, vb.z, vb.w};
#pragma unroll
        for (int c = 0; c < 8; ++c) {
            bf16 hi = f2b(v[c]);
            WTh[n0 + c][k] = hi;
            WTl[n0 + c][k] = f2b(v[c] - b2f(hi));
        }
    }
    __syncthreads();
    f32x4 acc[4];
#pragma unroll
    for (int t = 0; t < 4; ++t) acc[t] = {0.f, 0.f, 0.f, 0.f};
    const int m = lane & 15, quad = lane >> 4;
    const int rt = wave & 1, cH = wave >> 1;
    for (int kc = 0; kc < F_INF / 64; ++kc) {
        const int k0 = kc * 64;
        {
            int part = tid & 7;
            int r    = tid >> 3;
            const float* src = x + (size_t)(i0 + r) * F_INF + k0 + part * 8;
            float4 va = *(const float4*)(src);
            float4 vb = *(const float4*)(src + 4);
            float v[8] = {va.x, va.y, va.z, va.w, vb.x, vb.y, vb.z, vb.w};
            __align__(16) bf16 th[8];
            __align__(16) bf16 tl[8];
#pragma unroll
            for (int c = 0; c < 8; ++c) {
                bf16 hi = f2b(v[c]);
                th[c] = hi;
                tl[c] = f2b(v[c] - b2f(hi));
            }
            *(uint4*)(&XSh[r][part * 8]) = *(const uint4*)th;
            *(uint4*)(&XSl[r][part * 8]) = *(const uint4*)tl;
        }
        __syncthreads();
#pragma unroll
        for (int ks = 0; ks < 2; ++ks) {
            bf16x8 ah = *(const bf16x8*)(&XSh[rt * 16 + m][ks * 32 + quad * 8]);
            bf16x8 al = *(const bf16x8*)(&XSl[rt * 16 + m][ks * 32 + quad * 8]);
#pragma unroll
            for (int c = 0; c < 4; ++c) {
                const int ct = cH * 4 + c;
                bf16x8 bh = *(const bf16x8*)(&WTh[ct * 16 + m][k0 + ks * 32 + quad * 8]);
                bf16x8 bl = *(const bf16x8*)(&WTl[ct * 16 + m][k0 + ks * 32 + quad * 8]);
                acc[c] = __builtin_amdgcn_mfma_f32_16x16x32_bf16(al, bh, acc[c], 0, 0, 0);
                acc[c] = __builtin_amdgcn_mfma_f32_16x16x32_bf16(ah, bl, acc[c], 0, 0, 0);
                acc[c] = __builtin_amdgcn_mfma_f32_16x16x32_bf16(ah, bh, acc[c], 0, 0, 0);
            }
        }
        __syncthreads();
    }
    float p1[4] = {0.f, 0.f, 0.f, 0.f}, p2[4] = {0.f, 0.f, 0.f, 0.f};
#pragma unroll
    for (int c = 0; c < 4; ++c) {
        const int f = (cH * 4 + c) * 16 + m;
        const float w1 = a1s[f], w2 = a2s[f];
#pragma unroll
        for (int r = 0; r < 4; ++r) { p1[r] += acc[c][r] * w1; p2[r] += acc[c][r] * w2; }
    }
#pragma unroll
    for (int r = 0; r < 4; ++r) {
        const int row = rt * 16 + quad * 4 + r;
        atomicAdd(&s1L[row], p1[r]);
        atomicAdd(&s2L[row], p2[r]);
    }
#pragma unroll
    for (int c = 0; c < 4; ++c) {
        const int f = (cH * 4 + c) * 16 + m;
#pragma unroll
        for (int r = 0; r < 4; ++r) {
            const int i = i0 + rt * 16 + quad * 4 + r;
            hT[(size_t)f * N_NODES + i] = f2b(acc[c][r]);
        }
    }
    __syncthreads();
    if (tid < 32) {
        s1[i0 + tid] = s1L[tid];
        s2[i0 + tid] = s2L[tid];
        float m2 = s2L[tid];
#pragma unroll
        for (int s = 16; s > 0; s >>= 1) m2 = fmaxf(m2, __shfl_xor(m2, s));
        if (tid == 0) mgp[blockIdx.x] = m2;   // per-block max; k_attn reduces
    }
}

// ---------------- kernel 2: flash attention, gll double-buffer, 1 barrier/chunk ----------------
// block: 32 rows x 2048-col j-quarter, 256 thr = 4 waves. wave: rt=w&1, kh=w>>1.
// HS2: two 16 KB [128][64] bf16 buffers, content XOR-swizzled at 16B-slot
// granularity (slot ^= row&7). gll writes linear dest from pre-swizzled source.
__global__ __launch_bounds__(256, 4) void k_attn(const int* __restrict__ adj,
                                                 const float* __restrict__ s1g,
                                                 const float* __restrict__ s2g,
                                                 const float* __restrict__ mgp,
                                                 const bf16* __restrict__ hT,
                                                 float* __restrict__ Of,
                                                 float* __restrict__ lp) {
    __shared__ __align__(16) bf16 HS2[2][F_OUT][64];   // 32 KB total
    __shared__ float wred[4];
    __shared__ float lsum[32];
    const int tid  = threadIdx.x;
    const int lane = tid & 63, wave = tid >> 6;
    const int m = lane & 15, quad = lane >> 4;
    const int rt = wave & 1, kh = wave >> 1;
    const int i0    = blockIdx.x * 32;
    const int jq    = blockIdx.y;
    const int jbase = jq * 2048;
    const int irow  = i0 + rt * 16 + m;
    const float s1v = s1g[irow];
    // global max = max over 256 per-block maxima (replaces k_max kernel)
    float mv = mgp[tid];
#pragma unroll
    for (int s = 32; s > 0; s >>= 1) mv = fmaxf(mv, __shfl_xor(mv, s));
    if (lane == 0) wred[wave] = mv;
    if (tid < 32) lsum[tid] = 0.f;
    // staging geometry: thread (part=tid&7, fr=tid>>3) stages rows fr+g*32,
    // 16B slot 'part' of each row; SOURCE col-group pre-swizzled by fr&7.
    const int part = tid & 7, fr = tid >> 3;
    const int psw  = (part ^ (fr & 7)) * 8;
    const bf16* hTp = hT + jbase + psw;
    // prologue: stage chunk 0 into buf 0
#pragma unroll
    for (int g = 0; g < 4; ++g)
        gll16(hTp + (size_t)(fr + g * 32) * N_NODES, &HS2[0][fr + g * 32][part * 8]);
    const int jloc = kh * 32 + quad * 8;
    const int4*   arowp = (const int4*)(adj + (size_t)irow * N_NODES + jbase);
    const float4* srowp = (const float4*)(s2g + jbase);
    int4   avA = arowp[jloc / 4],     avB = arowp[jloc / 4 + 1];
    float4 svA = srowp[jloc / 4],     svB = srowp[jloc / 4 + 1];
    float lacc = 0.f;
    f32x4 acc[8];
#pragma unroll
    for (int c = 0; c < 8; ++c) acc[c] = {0.f, 0.f, 0.f, 0.f};
    __syncthreads();   // buf0 + wred ready (own gll drained by vmcnt(0))
    const float mgv = fmaxf(fmaxf(wred[0], wred[1]), fmaxf(wred[2], wred[3]));
    const float tmi = s1v + mgv;
    const float mi  = fmaxf(tmi, LRELU * tmi);  // >= every masked e of this row
    const int slotsw = ((kh * 4 + quad) ^ (m & 7)) * 8;  // swizzled read slot (elems)

    for (int jc = 0; jc < 32; ++jc) {
        const int cur = jc & 1;
        // 1) stage next chunk first (loads fly across compute, drained at barrier)
        if (jc < 31) {
#pragma unroll
            for (int g = 0; g < 4; ++g)
                gll16(hTp + (size_t)(fr + g * 32) * N_NODES + (jc + 1) * 64,
                      &HS2[cur ^ 1][fr + g * 32][part * 8]);
        }
        // 2) prefetch adj + s2 for next chunk into fresh regs
        const int jn = (jc < 31) ? jc + 1 : 31;
        int4   navA = arowp[jn * 16 + jloc / 4], navB = arowp[jn * 16 + jloc / 4 + 1];
        float4 nsvA = srowp[jn * 16 + jloc / 4], nsvB = srowp[jn * 16 + jloc / 4 + 1];
        // 3) P-compute for jc from current regs
        const int   am[8] = {avA.x, avA.y, avA.z, avA.w, avB.x, avB.y, avB.z, avB.w};
        const float sm[8] = {svA.x, svA.y, svA.z, svA.w, svB.x, svB.y, svB.z, svB.w};
        __align__(16) bf16 a8[8];
#pragma unroll
        for (int t = 0; t < 8; ++t) {
            float e = s1v + sm[t];
            e = fmaxf(e, LRELU * e);                // lrelu
            float w = (am[t] > 0) ? __expf(e - mi) : 0.f;
            bf16 b = f2b(w);
            a8[t] = b;
            lacc += b2f(b);                         // l matches MFMA operand rounding
        }
        bf16x8 afrag = *(const bf16x8*)a8;
        // 4) O[rt-tile][all 8 col-tiles] += P(kh half) @ h(kh half)
        __builtin_amdgcn_s_setprio(1);
#pragma unroll
        for (int c = 0; c < 8; ++c) {
            bf16x8 bfr = *(const bf16x8*)(&HS2[cur][c * 16 + m][slotsw]);
            acc[c] = __builtin_amdgcn_mfma_f32_16x16x32_bf16(afrag, bfr, acc[c], 0, 0, 0);
        }
        __builtin_amdgcn_s_setprio(0);
        avA = navA; avB = navB; svA = nsvA; svB = nsvB;
        __syncthreads();   // drains own gll (next buf ready) + own ds_reads
    }
    // l: reduce over quads (lanes m, m+16, m+32, m+48), one atomic per (row, kh)
    lacc += __shfl_xor(lacc, 16);
    lacc += __shfl_xor(lacc, 32);
    if (quad == 0) atomicAdd(&lsum[rt * 16 + m], lacc);
    __syncthreads();   // lsum complete; all MFMA done -> HS2 reusable as scratch
    if (tid < 32) lp[(size_t)jq * N_NODES + i0 + tid] = lsum[tid];
    float* scr = (float*)&HS2[0][0][0];   // 32x128 f32 = 16 KB
    if (kh == 1) {
#pragma unroll
        for (int c = 0; c < 8; ++c)
#pragma unroll
            for (int r = 0; r < 4; ++r)
                scr[(rt * 16 + quad * 4 + r) * 128 + c * 16 + m] = acc[c][r];
    }
    __syncthreads();
    if (kh == 0) {
#pragma unroll
        for (int c = 0; c < 8; ++c)
#pragma unroll
            for (int r = 0; r < 4; ++r) {
                const int row = rt * 16 + quad * 4 + r;
                const int f   = c * 16 + m;
                Of[((size_t)jq * N_NODES + i0 + row) * F_OUT + f] =
                    acc[c][r] + scr[row * 128 + f];
            }
    }
}

// ---------------- kernel 3: combine partials, normalize, ELU, f32 out ----------------
__global__ __launch_bounds__(256) void k_comb(const float* __restrict__ Of,
                                              const float* __restrict__ lp,
                                              float* __restrict__ out) {
    size_t gid = (size_t)blockIdx.x * 256 + threadIdx.x;  // i*128+f
    int i = (int)(gid >> 7);
    float s = 0.f, l = 0.f;
#pragma unroll
    for (int q = 0; q < 4; ++q) {
        s += Of[(size_t)q * (N_NODES * (size_t)F_OUT) + gid];
        l += lp[q * N_NODES + i];
    }
    float o = s / l;
    out[gid] = o > 0.f ? o : __expf(o) - 1.f;
}

extern "C" void kernel_launch(void* const* d_in, const int* in_sizes, int n_in,
                              void* d_out, int out_size, void* d_ws, size_t ws_size,
                              hipStream_t stream) {
    (void)out_size; (void)ws_size;
    const float* x   = nullptr;
    const int*   adj = nullptr;
    const float* W   = nullptr;
    const float* a   = nullptr;
    for (int ii = 0; ii < n_in; ++ii) {
        int sz = in_sizes[ii];
        if      (sz == N_NODES * F_INF)  x   = (const float*)d_in[ii];
        else if (sz == F_INF * F_OUT)    W   = (const float*)d_in[ii];
        else if (sz == 2 * F_OUT)        a   = (const float*)d_in[ii];
        else                             adj = (const int*)d_in[ii];
    }
    float* out = (float*)d_out;

    char* ws = (char*)d_ws;
    bf16*  hT  = (bf16*)ws;  ws += (size_t)F_OUT * N_NODES * 2;   // 2 MB
    float* s1  = (float*)ws; ws += N_NODES * 4;
    float* s2  = (float*)ws; ws += N_NODES * 4;
    float* mgp = (float*)ws; ws += 256 * 4;                       // per-block maxima
    float* lp  = (float*)ws; ws += 4 * N_NODES * 4;               // 128 KB
    float* Of  = (float*)ws;                                      // 16 MB

    k_xw  <<<N_NODES / 32, 256, 0, stream>>>(x, W, a, hT, s1, s2, mgp);
    k_attn<<<dim3(N_NODES / 32, 4), 256, 0, stream>>>(adj, s1, s2, mgp, hT, Of, lp);
    k_comb<<<(N_NODES * F_OUT) / 256, 256, 0, stream>>>(Of, lp, out);
}